// Round 5
// baseline (853.317 us; speedup 1.0000x reference)
//
#include <hip/hip_runtime.h>
#include <cstdint>
#include <cstddef>

typedef _Float16 f16;
typedef __attribute__((ext_vector_type(8))) _Float16 half8;
typedef __attribute__((ext_vector_type(8))) short short8;
typedef __attribute__((ext_vector_type(4))) float floatx4;

#define KDIM 256

__device__ __forceinline__ float sigm(float x) { return 1.0f / (1.0f + __expf(-x)); }

// C[M,N] = A[M,256] @ BT[N,256]^T ; fp16 in/out, fp32 accum. 64x64 tile/block.
__global__ __launch_bounds__(256) void gemm16(
    const f16* __restrict__ A, const f16* __restrict__ BT,
    f16* __restrict__ C, int ldc_)
{
  __shared__ short lA[64 * 136];
  __shared__ short lB[64 * 136];
  const int t = threadIdx.x;
  const int m0 = blockIdx.x * 64;
  const int n0 = blockIdx.y * 64;
  const int wave = t >> 6;
  const int lane = t & 63;
  const int ln = lane & 15;
  const int quad = lane >> 4;

  floatx4 acc[4];
#pragma unroll
  for (int i = 0; i < 4; ++i) acc[i] = (floatx4){0.f, 0.f, 0.f, 0.f};

#pragma unroll
  for (int kh = 0; kh < 2; ++kh) {
    const int k0 = kh * 128;
#pragma unroll
    for (int i = 0; i < 4; ++i) {
      int chunk = t + 256 * i;      // 64 rows x 16 chunks of 8 halves = 64x128
      int row = chunk >> 4;
      int cc = chunk & 15;
      *(short8*)&lA[row * 136 + cc * 8] =
          *(const short8*)(A + (size_t)(m0 + row) * KDIM + k0 + cc * 8);
      *(short8*)&lB[row * 136 + cc * 8] =
          *(const short8*)(BT + (size_t)(n0 + row) * KDIM + k0 + cc * 8);
    }
    __syncthreads();
#pragma unroll
    for (int ks = 0; ks < 4; ++ks) {
      const int kk = ks * 32 + quad * 8;
      half8 a = __builtin_bit_cast(half8,
          *(const short8*)&lA[(wave * 16 + ln) * 136 + kk]);
#pragma unroll
      for (int c = 0; c < 4; ++c) {
        half8 b = __builtin_bit_cast(half8,
            *(const short8*)&lB[(c * 16 + ln) * 136 + kk]);
        acc[c] = __builtin_amdgcn_mfma_f32_16x16x32_f16(a, b, acc[c], 0, 0, 0);
      }
    }
    __syncthreads();
  }
#pragma unroll
  for (int c = 0; c < 4; ++c) {
#pragma unroll
    for (int r = 0; r < 4; ++r) {
      int row = m0 + wave * 16 + quad * 4 + r;
      int col = n0 + c * 16 + ln;
      C[(size_t)row * ldc_ + col] = (f16)acc[c][r];
    }
  }
}

// fp32 inputs -> fp16 working copies (weights transposed K-contiguous)
__global__ __launch_bounds__(256) void prep(
    const float* __restrict__ emb, const float* __restrict__ Wioux,
    const float* __restrict__ Wfx, const float* __restrict__ Wiouh,
    const float* __restrict__ Wfh,
    f16* __restrict__ emb_h, f16* __restrict__ BTX,
    f16* __restrict__ WiouhT, f16* __restrict__ WfhT)
{
  int idx = blockIdx.x * 256 + threadIdx.x;   // 34048 blocks = 8,716,288
  if (idx < 8192000) {
    emb_h[idx] = (f16)emb[idx];
  } else if (idx < 8454144) {
    int r = idx - 8192000;                    // BTX[1024,256]: Wioux^T | Wfx^T
    int j = r >> 8, k = r & 255;
    BTX[r] = (f16)((j < 768) ? Wioux[(size_t)k * 768 + j]
                             : Wfx[(size_t)k * 256 + (j - 768)]);
  } else if (idx < 8650752) {
    int r = idx - 8454144;                    // WiouhT[768,256]
    int j = r >> 8, k = r & 255;
    WiouhT[r] = (f16)Wiouh[(size_t)k * 768 + j];
  } else {
    int r = idx - 8650752;                    // WfhT[256,256]
    int j = r >> 8, k = r & 255;
    WfhT[r] = (f16)Wfh[(size_t)k * 256 + j];
  }
}

// Fused per-level kernel: one block = 64 consecutive nodes.
// Phase 1: gates elementwise -> c (global fp32), h (d_out fp32), h16 -> LDS.
// Phase 2: hsum16[parent] = sum of 4 children h16 (block covers exactly 16 parents).
// Phase 3: FH[node] = h16 @ WfhT^T from LDS (consumed by the parent level).
__global__ __launch_bounds__(256) void level_fused(
    const int* __restrict__ tokens, const f16* __restrict__ TIOUF,
    const f16* __restrict__ IOUH, f16* FH,
    const f16* __restrict__ WfhT,
    const float* __restrict__ bioux, const float* __restrict__ biouh,
    const float* __restrict__ bfx, const float* __restrict__ bfh,
    float* cbuf, float* __restrict__ h, f16* __restrict__ hsum16,
    int s, int sz, int s_up, int sz_up, int leaf)
{
  __shared__ f16 hA[64 * 264];
  __shared__ f16 lB[64 * 264];
  __shared__ int ltok[64];

  const int t = threadIdx.x;
  const int base = s + 64 * blockIdx.x;
  const int lim = s + sz;

  if (t < 64) ltok[t] = (base + t < lim) ? tokens[base + t] : 0;
  __syncthreads();

  // ---- Phase 1: elementwise gates (thread t = dim m, loop over 64 nodes) ----
  const int m = t;
  const float bi0 = bioux[m] + biouh[m];
  const float bi1 = bioux[256 + m] + biouh[256 + m];
  const float bi2 = bioux[512 + m] + biouh[512 + m];
  const float bf = bfx[m] + bfh[m];
  for (int n = 0; n < 64; ++n) {
    int node = base + n;
    if (node < lim) {
      const f16* ti = TIOUF + (size_t)ltok[n] * 1024;
      float ip = (float)ti[m] + bi0;
      float op = (float)ti[256 + m] + bi1;
      float up = (float)ti[512 + m] + bi2;
      float cv;
      if (leaf) {
        cv = sigm(ip) * tanhf(up);
      } else {
        const f16* io = IOUH + (size_t)(node - s) * 768;
        ip += (float)io[m];
        op += (float)io[256 + m];
        up += (float)io[512 + m];
        float xff = (float)ti[768 + m] + bf;
        cv = sigm(ip) * tanhf(up);
        size_t ch = 4 * (size_t)node + 1;
#pragma unroll
        for (int k = 0; k < 4; ++k) {
          float fk = sigm((float)FH[(ch + k) * 256 + m] + xff);
          cv += fk * cbuf[(ch + k) * 256 + m];
        }
      }
      float hv = sigm(op) * tanhf(cv);
      cbuf[(size_t)node * 256 + m] = cv;
      h[(size_t)node * 256 + m] = hv;
      hA[n * 264 + m] = (f16)hv;
    } else {
      hA[n * 264 + m] = (f16)0.f;
    }
  }
  __syncthreads();

  // ---- Phase 2: hsum for the 16 parents covered by this block ----
  if (s_up >= 0) {
    int P0 = (base - 1) >> 2;   // parent of first node (base >= 1 here)
#pragma unroll
    for (int p = 0; p < 16; ++p) {
      if (P0 + p < s_up + sz_up) {
        float v = (float)hA[(4 * p + 0) * 264 + m] + (float)hA[(4 * p + 1) * 264 + m] +
                  (float)hA[(4 * p + 2) * 264 + m] + (float)hA[(4 * p + 3) * 264 + m];
        hsum16[(size_t)(P0 + p - s_up) * 256 + m] = (f16)v;
      }
    }
  }

  // ---- Phase 3: FH = h16 @ WfhT^T (skip for root; nobody consumes it) ----
  if (s != 0) {
    const int wave = t >> 6;
    const int lane = t & 63;
    const int ln = lane & 15;
    const int quad = lane >> 4;
    for (int nc = 0; nc < 4; ++nc) {
      const int n0 = nc * 64;
      // stage WfhT rows n0..n0+63, full K=256 (2048 chunks of 8 halves)
#pragma unroll
      for (int i = 0; i < 8; ++i) {
        int chunk = t + 256 * i;
        int row = chunk >> 5;
        int cc = chunk & 31;
        *(short8*)&lB[row * 264 + cc * 8] =
            *(const short8*)(WfhT + (size_t)(n0 + row) * 256 + cc * 8);
      }
      __syncthreads();
      floatx4 acc[4];
#pragma unroll
      for (int i = 0; i < 4; ++i) acc[i] = (floatx4){0.f, 0.f, 0.f, 0.f};
#pragma unroll
      for (int ks = 0; ks < 8; ++ks) {
        const int kk = ks * 32 + quad * 8;
        half8 a = __builtin_bit_cast(half8,
            *(const short8*)&hA[(wave * 16 + ln) * 264 + kk]);
#pragma unroll
        for (int c = 0; c < 4; ++c) {
          half8 b = __builtin_bit_cast(half8,
              *(const short8*)&lB[(c * 16 + ln) * 264 + kk]);
          acc[c] = __builtin_amdgcn_mfma_f32_16x16x32_f16(a, b, acc[c], 0, 0, 0);
        }
      }
#pragma unroll
      for (int c = 0; c < 4; ++c) {
#pragma unroll
        for (int r = 0; r < 4; ++r) {
          int row = wave * 16 + quad * 4 + r;     // local node index
          int col = n0 + c * 16 + ln;
          FH[((size_t)(base + row)) * 256 + col] = (f16)acc[c][r];
        }
      }
      __syncthreads();
    }
  }
}

extern "C" void kernel_launch(void* const* d_in, const int* in_sizes, int n_in,
                              void* d_out, int out_size, void* d_ws, size_t ws_size,
                              hipStream_t stream) {
  const int*   tokens = (const int*)d_in[0];
  const float* emb    = (const float*)d_in[2];
  const float* Wioux  = (const float*)d_in[3];
  const float* bioux  = (const float*)d_in[4];
  const float* Wiouh  = (const float*)d_in[5];
  const float* biouh  = (const float*)d_in[6];
  const float* Wfx    = (const float*)d_in[7];
  const float* bfx    = (const float*)d_in[8];
  const float* Wfh    = (const float*)d_in[9];
  const float* bfh    = (const float*)d_in[10];
  float* h = (float*)d_out;   // fp32 h master = output [87381,256]
  (void)in_sizes; (void)n_in; (void)out_size; (void)ws_size;

  // workspace (~251 MB)
  f16* emb_h   = (f16*)d_ws;                        //  8,192,000
  f16* BTX     = emb_h   + 8192000;                 //    262,144
  f16* WiouhT  = BTX     + 262144;                  //    196,608
  f16* WfhT    = WiouhT  + 196608;                  //     65,536
  f16* TIOUF   = WfhT    + 65536;                   // 32,768,000 (32000x1024)
  f16* IOUH    = TIOUF   + (size_t)32768000;        // 12,582,912 (16384x768)
  f16* FH      = IOUH    + (size_t)12582912;        // 22,396,928 (87488x256)
  f16* hsum16  = FH      + (size_t)22396928;        //  4,194,304 (16384x256)
  float* cbuf  = (float*)(hsum16 + (size_t)4194304); // 87488x256 fp32

  // 0. convert inputs to fp16 working copies
  prep<<<34048, 256, 0, stream>>>(emb, Wioux, Wfx, Wiouh, Wfh,
                                  emb_h, BTX, WiouhT, WfhT);

  // 1. vocab table: TIOUF[v] = emb[v] @ [Wioux | Wfx]  (32000 x 1024)
  gemm16<<<dim3(500, 16), 256, 0, stream>>>(emb_h, BTX, TIOUF, 1024);

  // 2. leaves: fused gates + hsum + FH   (s=21845, sz=65536)
  level_fused<<<1024, 256, 0, stream>>>(tokens, TIOUF, nullptr, FH, WfhT,
                                        bioux, biouh, bfx, bfh, cbuf, h, hsum16,
                                        21845, 65536, 5461, 16384, 1);

  // 3. internal levels, leaves-1 up to root: IOUH GEMM + fused level kernel
  const int LS[8][4] = {{5461, 16384, 1365, 4096}, {1365, 4096, 341, 1024},
                        {341, 1024, 85, 256},      {85, 256, 21, 64},
                        {21, 64, 5, 16},           {5, 16, 1, 4},
                        {1, 4, 0, 1},              {0, 1, -1, 0}};
  for (int i = 0; i < 8; ++i) {
    int s = LS[i][0], sz = LS[i][1], s_up = LS[i][2], sz_up = LS[i][3];
    int mt = (sz + 63) / 64;
    gemm16<<<dim3(mt, 12), 256, 0, stream>>>(hsum16, WiouhT, IOUH, 768);
    level_fused<<<mt, 256, 0, stream>>>(tokens, TIOUF, IOUH, FH, WfhT,
                                        bioux, biouh, bfx, bfh, cbuf, h, hsum16,
                                        s, sz, s_up, sz_up, 0);
  }
}

// Round 6
// 438.609 us; speedup vs baseline: 1.9455x; 1.9455x over previous
//
#include <hip/hip_runtime.h>
#include <cstdint>
#include <cstddef>

typedef _Float16 f16;
typedef __attribute__((ext_vector_type(8))) _Float16 half8;
typedef __attribute__((ext_vector_type(8))) short short8;
typedef __attribute__((ext_vector_type(4))) float floatx4;

__device__ __forceinline__ float sigm(float x) { return 1.0f / (1.0f + __expf(-x)); }

// Dual-job 128x128-tile GEMM: C[M,N] = A[M,256] @ BT[N,256]^T, fp16 in/out,
// fp32 accum. Grid = tiles0 + tiles1 blocks; job0 first. Buffers must be
// padded so every 128-row tile is readable/writable (garbage rows OK).
// 4 waves in 2x2; per wave 64x64 via 4x4 mfma_16x16x32 frags. LDS 36.9 KB.
__global__ __launch_bounds__(256) void gemm128d(
    const f16* __restrict__ A0, const f16* __restrict__ B0, f16* __restrict__ C0,
    int ldc0, int nt0, int tiles0,
    const f16* __restrict__ A1, const f16* __restrict__ B1, f16* __restrict__ C1,
    int ldc1, int nt1)
{
  const f16* A; const f16* BT; f16* C; int ldc_, mi, ni;
  int bid = blockIdx.x;
  if (bid < tiles0) { A = A0; BT = B0; C = C0; ldc_ = ldc0; mi = bid / nt0; ni = bid % nt0; }
  else { int r = bid - tiles0; A = A1; BT = B1; C = C1; ldc_ = ldc1; mi = r / nt1; ni = r % nt1; }
  const int m0 = mi * 128;
  const int n0 = ni * 128;

  __shared__ short lA[128 * 72];
  __shared__ short lB[128 * 72];
  const int t = threadIdx.x;
  const int wave = t >> 6;
  const int lane = t & 63;
  const int ln = lane & 15;
  const int quad = lane >> 4;
  const int wr = wave >> 1;           // wave row (0/1) -> 64 rows
  const int wc = wave & 1;            // wave col (0/1) -> 64 cols

  floatx4 acc[4][4];
#pragma unroll
  for (int i = 0; i < 4; ++i)
#pragma unroll
    for (int j = 0; j < 4; ++j) acc[i][j] = (floatx4){0.f, 0.f, 0.f, 0.f};

#pragma unroll
  for (int st = 0; st < 4; ++st) {    // K = 256 in 4 stages of 64
    const int k0 = st * 64;
#pragma unroll
    for (int i = 0; i < 4; ++i) {     // 1024 chunks of 8 halves: 128 rows x 8
      int chunk = t + 256 * i;
      int row = chunk >> 3;
      int cc = chunk & 7;
      *(short8*)&lA[row * 72 + cc * 8] =
          *(const short8*)(A + (size_t)(m0 + row) * 256 + k0 + cc * 8);
      *(short8*)&lB[row * 72 + cc * 8] =
          *(const short8*)(BT + (size_t)(n0 + row) * 256 + k0 + cc * 8);
    }
    __syncthreads();
#pragma unroll
    for (int ks = 0; ks < 2; ++ks) {
      const int kk = ks * 32 + quad * 8;
      half8 a[4], b[4];
#pragma unroll
      for (int rf = 0; rf < 4; ++rf)
        a[rf] = __builtin_bit_cast(half8,
            *(const short8*)&lA[(wr * 64 + rf * 16 + ln) * 72 + kk]);
#pragma unroll
      for (int cf = 0; cf < 4; ++cf)
        b[cf] = __builtin_bit_cast(half8,
            *(const short8*)&lB[(wc * 64 + cf * 16 + ln) * 72 + kk]);
#pragma unroll
      for (int rf = 0; rf < 4; ++rf)
#pragma unroll
        for (int cf = 0; cf < 4; ++cf)
          acc[rf][cf] = __builtin_amdgcn_mfma_f32_16x16x32_f16(
              a[rf], b[cf], acc[rf][cf], 0, 0, 0);
    }
    __syncthreads();
  }
  // D layout: col = lane&15, row = quad*4 + reg
#pragma unroll
  for (int rf = 0; rf < 4; ++rf)
#pragma unroll
    for (int cf = 0; cf < 4; ++cf)
#pragma unroll
      for (int r = 0; r < 4; ++r) {
        int row = m0 + wr * 64 + rf * 16 + quad * 4 + r;
        int col = n0 + wc * 64 + cf * 16 + ln;
        C[(size_t)row * ldc_ + col] = (f16)acc[rf][cf][r];
      }
}

// fp32 inputs -> fp16 working copies (weights transposed K-contiguous)
__global__ __launch_bounds__(256) void prep(
    const float* __restrict__ emb, const float* __restrict__ Wioux,
    const float* __restrict__ Wfx, const float* __restrict__ Wiouh,
    const float* __restrict__ Wfh,
    f16* __restrict__ emb_h, f16* __restrict__ BTX,
    f16* __restrict__ WiouhT, f16* __restrict__ WfhT)
{
  int idx = blockIdx.x * 256 + threadIdx.x;   // 34048 blocks = 8,716,288
  if (idx < 8192000) {
    emb_h[idx] = (f16)emb[idx];
  } else if (idx < 8454144) {
    int r = idx - 8192000;                    // BTX[1024,256]: Wioux^T | Wfx^T
    int j = r >> 8, k = r & 255;
    BTX[r] = (f16)((j < 768) ? Wioux[(size_t)k * 768 + j]
                             : Wfx[(size_t)k * 256 + (j - 768)]);
  } else if (idx < 8650752) {
    int r = idx - 8454144;                    // WiouhT[768,256]
    int j = r >> 8, k = r & 255;
    WiouhT[r] = (f16)Wiouh[(size_t)k * 768 + j];
  } else {
    int r = idx - 8650752;                    // WfhT[256,256]
    int j = r >> 8, k = r & 255;
    WfhT[r] = (f16)Wfh[(size_t)k * 256 + j];
  }
}

// One block = 4 sibling nodes (one parent). thread = dim m. Computes gates,
// writes c16 / h(fp32,d_out) / h16, and the parent's hsum16 from registers.
__global__ __launch_bounds__(256) void elem4(
    const int* __restrict__ tokens, const f16* __restrict__ TIOUF,
    const f16* __restrict__ IOUH, const f16* __restrict__ FH,
    const float* __restrict__ bioux, const float* __restrict__ biouh,
    const float* __restrict__ bfx, const float* __restrict__ bfh,
    f16* __restrict__ c16, float* __restrict__ h, f16* __restrict__ h16,
    f16* __restrict__ hsum16, int s, int sz, int s_up, int leaf)
{
  const int m = threadIdx.x;
  const int n0 = s + 4 * blockIdx.x;
  const int lim = s + sz;
  const float bi0 = bioux[m] + biouh[m];
  const float bi1 = bioux[256 + m] + biouh[256 + m];
  const float bi2 = bioux[512 + m] + biouh[512 + m];
  const float bf = bfx[m] + bfh[m];
  float hs = 0.f;
#pragma unroll
  for (int n = 0; n < 4; ++n) {
    int node = n0 + n;
    if (node < lim) {
      const f16* ti = TIOUF + (size_t)tokens[node] * 1024;
      float ip = (float)ti[m] + bi0;
      float op = (float)ti[256 + m] + bi1;
      float up = (float)ti[512 + m] + bi2;
      float cv;
      if (leaf) {
        cv = sigm(ip) * tanhf(up);
      } else {
        const f16* io = IOUH + (size_t)(node - s) * 768;
        ip += (float)io[m];
        op += (float)io[256 + m];
        up += (float)io[512 + m];
        float xff = (float)ti[768 + m] + bf;
        cv = sigm(ip) * tanhf(up);
        size_t ch = 4 * (size_t)node + 1;
#pragma unroll
        for (int k = 0; k < 4; ++k) {
          float fk = sigm((float)FH[(ch + k) * 256 + m] + xff);
          cv += fk * (float)c16[(ch + k) * 256 + m];
        }
      }
      float hv = sigm(op) * tanhf(cv);
      c16[(size_t)node * 256 + m] = (f16)cv;
      h[(size_t)node * 256 + m] = hv;
      h16[(size_t)node * 256 + m] = (f16)hv;
      hs += hv;
    }
  }
  if (s_up >= 0)
    hsum16[(size_t)((n0 - 1) / 4 - s_up) * 256 + m] = (f16)hs;
}

extern "C" void kernel_launch(void* const* d_in, const int* in_sizes, int n_in,
                              void* d_out, int out_size, void* d_ws, size_t ws_size,
                              hipStream_t stream) {
  const int*   tokens = (const int*)d_in[0];
  const float* emb    = (const float*)d_in[2];
  const float* Wioux  = (const float*)d_in[3];
  const float* bioux  = (const float*)d_in[4];
  const float* Wiouh  = (const float*)d_in[5];
  const float* biouh  = (const float*)d_in[6];
  const float* Wfx    = (const float*)d_in[7];
  const float* bfx    = (const float*)d_in[8];
  const float* Wfh    = (const float*)d_in[9];
  const float* bfh    = (const float*)d_in[10];
  float* h = (float*)d_out;   // fp32 h master = output [87381,256]
  (void)in_sizes; (void)n_in; (void)out_size; (void)ws_size;

  // workspace: all f16, ~252 MB
  f16* emb_h   = (f16*)d_ws;                        //  8,192,000
  f16* BTX     = emb_h   + 8192000;                 //    262,144
  f16* WiouhT  = BTX     + 262144;                  //    196,608
  f16* WfhT    = WiouhT  + 196608;                  //     65,536
  f16* TIOUF   = WfhT    + 65536;                   // 32,768,000 (32000x1024)
  f16* IOUH    = TIOUF   + (size_t)32768000;        // 12,582,912 (16384x768)
  f16* FH      = IOUH    + (size_t)12582912;        // 22,396,928 (87488x256)
  f16* h16     = FH      + (size_t)22396928;        // 22,396,928 (87488x256)
  f16* hsum16  = h16     + (size_t)22396928;        //  4,194,304 (16384x256)
  f16* c16     = hsum16  + (size_t)4194304;         // 22,396,928 (87488x256)

  // 0. convert inputs to fp16 working copies
  prep<<<34048, 256, 0, stream>>>(emb, Wioux, Wfx, Wiouh, Wfh,
                                  emb_h, BTX, WiouhT, WfhT);

  // 1. vocab table: TIOUF[v] = emb[v] @ [Wioux | Wfx]  (32000x1024, 250x8 tiles)
  gemm128d<<<2000, 256, 0, stream>>>(emb_h, BTX, TIOUF, 1024, 8, 2000,
                                     emb_h, BTX, TIOUF, 1024, 8);

  // levels, leaves -> root: (start, size)
  const int LV[9][2] = {{21845, 65536}, {5461, 16384}, {1365, 4096},
                        {341, 1024},    {85, 256},     {21, 64},
                        {5, 16},        {1, 4},        {0, 1}};

  // 2. leaves: gates + hsum16 (parents at 5461)
  elem4<<<16384, 256, 0, stream>>>(tokens, TIOUF, nullptr, nullptr,
                                   bioux, biouh, bfx, bfh,
                                   c16, h, h16, hsum16, 21845, 65536, 5461, 1);

  // 3. per level: one dual GEMM (FH of level below + IOUH of this level), then elem4
  for (int i = 1; i < 9; ++i) {
    int ps = LV[i - 1][0], psz = LV[i - 1][1];
    int s = LV[i][0], sz = LV[i][1];
    int mt0 = (psz + 127) / 128;          // FH tiles (N=256 -> nt0=2)
    int mt1 = (sz + 127) / 128;           // IOUH tiles (N=768 -> nt1=6)
    int tiles0 = mt0 * 2;
    int total = tiles0 + mt1 * 6;
    gemm128d<<<total, 256, 0, stream>>>(
        h16 + (size_t)ps * 256, WfhT, FH + (size_t)ps * 256, 256, 2, tiles0,
        hsum16, WiouhT, IOUH, 768, 6);
    int s_up = (i < 8) ? LV[i + 1][0] : -1;
    int blocks = (sz + 3) / 4;
    elem4<<<blocks, 256, 0, stream>>>(tokens, TIOUF, IOUH, FH,
                                      bioux, biouh, bfx, bfh,
                                      c16, h, h16, hsum16, s, sz, s_up, 0);
  }
}

// Round 7
// 413.887 us; speedup vs baseline: 2.0617x; 1.0597x over previous
//
#include <hip/hip_runtime.h>
#include <cstdint>
#include <cstddef>

typedef _Float16 f16;
typedef __attribute__((ext_vector_type(8))) _Float16 half8;
typedef __attribute__((ext_vector_type(4))) _Float16 half4;
typedef __attribute__((ext_vector_type(8))) short short8;
typedef __attribute__((ext_vector_type(4))) float floatx4;
typedef __attribute__((ext_vector_type(8))) float floatx8;

__device__ __forceinline__ float rcp_(float x) { return __builtin_amdgcn_rcpf(x); }
__device__ __forceinline__ float sigm(float x) { return rcp_(1.f + __expf(-x)); }
__device__ __forceinline__ float tanh_(float x) { return 1.f - 2.f * rcp_(1.f + __expf(2.f * x)); }

// Dual-job 128x128-tile GEMM: C[M,N] = A[M,256] @ BT[N,256]^T, fp16 in/out,
// fp32 accum. Grid = tiles0 + tiles1 blocks; job0 first. Buffers padded so
// every 128-row tile is readable/writable (garbage rows OK). LDS 36 KB.
__global__ __launch_bounds__(256) void gemm128d(
    const f16* __restrict__ A0, const f16* __restrict__ B0, f16* __restrict__ C0,
    int ldc0, int nt0, int tiles0,
    const f16* __restrict__ A1, const f16* __restrict__ B1, f16* __restrict__ C1,
    int ldc1, int nt1)
{
  const f16* A; const f16* BT; f16* C; int ldc_, mi, ni;
  int bid = blockIdx.x;
  if (bid < tiles0) { A = A0; BT = B0; C = C0; ldc_ = ldc0; mi = bid / nt0; ni = bid % nt0; }
  else { int r = bid - tiles0; A = A1; BT = B1; C = C1; ldc_ = ldc1; mi = r / nt1; ni = r % nt1; }
  const int m0 = mi * 128;
  const int n0 = ni * 128;

  __shared__ short lA[128 * 72];
  __shared__ short lB[128 * 72];
  const int t = threadIdx.x;
  const int wave = t >> 6;
  const int lane = t & 63;
  const int ln = lane & 15;
  const int quad = lane >> 4;
  const int wr = wave >> 1;
  const int wc = wave & 1;

  floatx4 acc[4][4];
#pragma unroll
  for (int i = 0; i < 4; ++i)
#pragma unroll
    for (int j = 0; j < 4; ++j) acc[i][j] = (floatx4){0.f, 0.f, 0.f, 0.f};

#pragma unroll
  for (int st = 0; st < 4; ++st) {    // K = 256 in 4 stages of 64
    const int k0 = st * 64;
#pragma unroll
    for (int i = 0; i < 4; ++i) {     // 128 rows x 8 chunks of 8 halves
      int chunk = t + 256 * i;
      int row = chunk >> 3;
      int cc = chunk & 7;
      *(short8*)&lA[row * 72 + cc * 8] =
          *(const short8*)(A + (size_t)(m0 + row) * 256 + k0 + cc * 8);
      *(short8*)&lB[row * 72 + cc * 8] =
          *(const short8*)(BT + (size_t)(n0 + row) * 256 + k0 + cc * 8);
    }
    __syncthreads();
#pragma unroll
    for (int ks = 0; ks < 2; ++ks) {
      const int kk = ks * 32 + quad * 8;
      half8 a[4], b[4];
#pragma unroll
      for (int rf = 0; rf < 4; ++rf)
        a[rf] = __builtin_bit_cast(half8,
            *(const short8*)&lA[(wr * 64 + rf * 16 + ln) * 72 + kk]);
#pragma unroll
      for (int cf = 0; cf < 4; ++cf)
        b[cf] = __builtin_bit_cast(half8,
            *(const short8*)&lB[(wc * 64 + cf * 16 + ln) * 72 + kk]);
#pragma unroll
      for (int rf = 0; rf < 4; ++rf)
#pragma unroll
        for (int cf = 0; cf < 4; ++cf)
          acc[rf][cf] = __builtin_amdgcn_mfma_f32_16x16x32_f16(
              a[rf], b[cf], acc[rf][cf], 0, 0, 0);
    }
    __syncthreads();
  }
#pragma unroll
  for (int rf = 0; rf < 4; ++rf)
#pragma unroll
    for (int cf = 0; cf < 4; ++cf)
#pragma unroll
      for (int r = 0; r < 4; ++r) {
        int row = m0 + wr * 64 + rf * 16 + quad * 4 + r;
        int col = n0 + wc * 64 + cf * 16 + ln;
        C[(size_t)row * ldc_ + col] = (f16)acc[rf][cf][r];
      }
}

// fp32 inputs -> fp16 working copies (emb vectorized 4-wide; weights transposed)
__global__ __launch_bounds__(256) void prep(
    const float* __restrict__ emb, const float* __restrict__ Wioux,
    const float* __restrict__ Wfx, const float* __restrict__ Wiouh,
    const float* __restrict__ Wfh,
    f16* __restrict__ emb_h, f16* __restrict__ BTX,
    f16* __restrict__ WiouhT, f16* __restrict__ WfhT)
{
  int idx = blockIdx.x * 256 + threadIdx.x;   // 10049 blocks = 2,572,544
  if (idx < 2048000) {                        // emb: 4 elems/thread
    floatx4 v = *(const floatx4*)(emb + 4 * (size_t)idx);
    half4 o;
#pragma unroll
    for (int j = 0; j < 4; ++j) o[j] = (f16)v[j];
    *(half4*)(emb_h + 4 * (size_t)idx) = o;
  } else if (idx < 2310144) {
    int r = idx - 2048000;                    // BTX[1024,256]: Wioux^T | Wfx^T
    int j = r >> 8, k = r & 255;
    BTX[r] = (f16)((j < 768) ? Wioux[(size_t)k * 768 + j]
                             : Wfx[(size_t)k * 256 + (j - 768)]);
  } else if (idx < 2506752) {
    int r = idx - 2310144;                    // WiouhT[768,256]
    int j = r >> 8, k = r & 255;
    WiouhT[r] = (f16)Wiouh[(size_t)k * 768 + j];
  } else {
    int r = idx - 2506752;                    // WfhT[256,256]
    int j = r >> 8, k = r & 255;
    WfhT[r] = (f16)Wfh[(size_t)k * 256 + j];
  }
}

// block = 8 nodes (2 parents); thread t -> node t>>5, dims 8*(t&31)..+7.
// All global accesses 16-32 B/lane. Gates -> c16/h/h16; parent hsum16 via LDS.
__global__ __launch_bounds__(256) void elem8(
    const int* __restrict__ tokens, const f16* __restrict__ TIOUF,
    const f16* __restrict__ IOUH, const f16* __restrict__ FH,
    const float* __restrict__ bioux, const float* __restrict__ biouh,
    const float* __restrict__ bfx, const float* __restrict__ bfh,
    f16* __restrict__ c16, float* __restrict__ h, f16* __restrict__ h16,
    f16* __restrict__ hsum16, int s, int sz, int s_up, int sz_up, int leaf)
{
  __shared__ float hsh[8 * 260];
  const int t = threadIdx.x;
  const int nloc = t >> 5;
  const int d0 = (t & 31) * 8;
  const int base = s + 8 * blockIdx.x;
  const int node = base + nloc;
  const int lim = s + sz;

  if (node < lim) {
    const f16* ti = TIOUF + (size_t)tokens[node] * 1024;
    half8 t0 = *(const half8*)(ti + d0);
    half8 t1 = *(const half8*)(ti + 256 + d0);
    half8 t2 = *(const half8*)(ti + 512 + d0);
    floatx8 bi0 = *(const floatx8*)(bioux + d0) + *(const floatx8*)(biouh + d0);
    floatx8 bi1 = *(const floatx8*)(bioux + 256 + d0) + *(const floatx8*)(biouh + 256 + d0);
    floatx8 bi2 = *(const floatx8*)(bioux + 512 + d0) + *(const floatx8*)(biouh + 512 + d0);

    float cv[8];
    if (leaf) {
#pragma unroll
      for (int j = 0; j < 8; ++j)
        cv[j] = sigm((float)t0[j] + bi0[j]) * tanh_((float)t2[j] + bi2[j]);
    } else {
      const f16* io = IOUH + (size_t)(node - s) * 768;
      half8 io0 = *(const half8*)(io + d0);
      half8 io1 = *(const half8*)(io + 256 + d0);
      half8 io2 = *(const half8*)(io + 512 + d0);
      half8 t3 = *(const half8*)(ti + 768 + d0);
      floatx8 bff = *(const floatx8*)(bfx + d0) + *(const floatx8*)(bfh + d0);
      size_t ch = 4 * (size_t)node + 1;
      half8 fh0 = *(const half8*)(FH + (ch + 0) * 256 + d0);
      half8 fh1 = *(const half8*)(FH + (ch + 1) * 256 + d0);
      half8 fh2 = *(const half8*)(FH + (ch + 2) * 256 + d0);
      half8 fh3 = *(const half8*)(FH + (ch + 3) * 256 + d0);
      half8 cc0 = *(const half8*)(c16 + (ch + 0) * 256 + d0);
      half8 cc1 = *(const half8*)(c16 + (ch + 1) * 256 + d0);
      half8 cc2 = *(const half8*)(c16 + (ch + 2) * 256 + d0);
      half8 cc3 = *(const half8*)(c16 + (ch + 3) * 256 + d0);
#pragma unroll
      for (int j = 0; j < 8; ++j) {
        float xff = (float)t3[j] + bff[j];
        float v = sigm((float)t0[j] + (float)io0[j] + bi0[j]) *
                  tanh_((float)t2[j] + (float)io2[j] + bi2[j]);
        v += sigm((float)fh0[j] + xff) * (float)cc0[j];
        v += sigm((float)fh1[j] + xff) * (float)cc1[j];
        v += sigm((float)fh2[j] + xff) * (float)cc2[j];
        v += sigm((float)fh3[j] + xff) * (float)cc3[j];
        cv[j] = v;
      }
      t1 = __builtin_bit_cast(half8,
           __builtin_bit_cast(short8, t1));  // keep t1 live; o-gate adds io1 below
#pragma unroll
      for (int j = 0; j < 8; ++j) bi1[j] += (float)io1[j];
    }

    half8 c8, h8;
    floatx8 hf;
#pragma unroll
    for (int j = 0; j < 8; ++j) {
      float hv = sigm((float)t1[j] + bi1[j]) * tanh_(cv[j]);
      c8[j] = (f16)cv[j];
      h8[j] = (f16)hv;
      hf[j] = hv;
    }
    *(half8*)(c16 + (size_t)node * 256 + d0) = c8;
    *(floatx8*)(h + (size_t)node * 256 + d0) = hf;
    *(half8*)(h16 + (size_t)node * 256 + d0) = h8;
    *(floatx8*)&hsh[nloc * 260 + d0] = hf;
  }
  __syncthreads();

  if (s_up >= 0 && t < 64) {
    int p = t >> 5;
    int dd = (t & 31) * 8;
    int parent = ((base - 1) >> 2) + p;
    if (parent < s_up + sz_up) {
      floatx8 v = *(const floatx8*)&hsh[(4 * p + 0) * 260 + dd] +
                  *(const floatx8*)&hsh[(4 * p + 1) * 260 + dd] +
                  *(const floatx8*)&hsh[(4 * p + 2) * 260 + dd] +
                  *(const floatx8*)&hsh[(4 * p + 3) * 260 + dd];
      half8 o;
#pragma unroll
      for (int j = 0; j < 8; ++j) o[j] = (f16)v[j];
      *(half8*)(hsum16 + (size_t)(parent - s_up) * 256 + dd) = o;
    }
  }
}

extern "C" void kernel_launch(void* const* d_in, const int* in_sizes, int n_in,
                              void* d_out, int out_size, void* d_ws, size_t ws_size,
                              hipStream_t stream) {
  const int*   tokens = (const int*)d_in[0];
  const float* emb    = (const float*)d_in[2];
  const float* Wioux  = (const float*)d_in[3];
  const float* bioux  = (const float*)d_in[4];
  const float* Wiouh  = (const float*)d_in[5];
  const float* biouh  = (const float*)d_in[6];
  const float* Wfx    = (const float*)d_in[7];
  const float* bfx    = (const float*)d_in[8];
  const float* Wfh    = (const float*)d_in[9];
  const float* bfh    = (const float*)d_in[10];
  float* h = (float*)d_out;   // fp32 h master = output [87381,256]
  (void)in_sizes; (void)n_in; (void)out_size; (void)ws_size;

  // workspace: all f16, ~252 MB
  f16* emb_h   = (f16*)d_ws;                        //  8,192,000
  f16* BTX     = emb_h   + 8192000;                 //    262,144
  f16* WiouhT  = BTX     + 262144;                  //    196,608
  f16* WfhT    = WiouhT  + 196608;                  //     65,536
  f16* TIOUF   = WfhT    + 65536;                   // 32,768,000 (32000x1024)
  f16* IOUH    = TIOUF   + (size_t)32768000;        // 12,582,912 (16384x768)
  f16* FH      = IOUH    + (size_t)12582912;        // 22,396,928 (87488x256)
  f16* h16     = FH      + (size_t)22396928;        // 22,396,928 (87488x256)
  f16* hsum16  = h16     + (size_t)22396928;        //  4,194,304 (16384x256)
  f16* c16     = hsum16  + (size_t)4194304;         // 22,396,928 (87488x256)

  // 0. convert inputs to fp16 working copies
  prep<<<10049, 256, 0, stream>>>(emb, Wioux, Wfx, Wiouh, Wfh,
                                  emb_h, BTX, WiouhT, WfhT);

  // 1. vocab table: TIOUF[v] = emb[v] @ [Wioux | Wfx]  (32000x1024, 250x8 tiles)
  gemm128d<<<2000, 256, 0, stream>>>(emb_h, BTX, TIOUF, 1024, 8, 2000,
                                     emb_h, BTX, TIOUF, 1024, 8);

  // levels, leaves -> root: (start, size)
  const int LV[9][2] = {{21845, 65536}, {5461, 16384}, {1365, 4096},
                        {341, 1024},    {85, 256},     {21, 64},
                        {5, 16},        {1, 4},        {0, 1}};

  // 2. leaves: gates + hsum16 (parents at 5461)
  elem8<<<8192, 256, 0, stream>>>(tokens, TIOUF, nullptr, nullptr,
                                  bioux, biouh, bfx, bfh,
                                  c16, h, h16, hsum16, 21845, 65536, 5461, 16384, 1);

  // 3. per level: one dual GEMM (FH of level below + IOUH of this level), then elem8
  for (int i = 1; i < 9; ++i) {
    int ps = LV[i - 1][0], psz = LV[i - 1][1];
    int s = LV[i][0], sz = LV[i][1];
    int mt0 = (psz + 127) / 128;          // FH tiles (N=256 -> nt0=2)
    int mt1 = (sz + 127) / 128;           // IOUH tiles (N=768 -> nt1=6)
    int tiles0 = mt0 * 2;
    int total = tiles0 + mt1 * 6;
    gemm128d<<<total, 256, 0, stream>>>(
        h16 + (size_t)ps * 256, WfhT, FH + (size_t)ps * 256, 256, 2, tiles0,
        hsum16, WiouhT, IOUH, 768, 6);
    int s_up = (i < 8) ? LV[i + 1][0] : -1;
    int sz_up = (i < 8) ? LV[i + 1][1] : 0;
    int blocks = (sz + 7) / 8;
    elem8<<<blocks, 256, 0, stream>>>(tokens, TIOUF, IOUH, FH,
                                      bioux, biouh, bfx, bfh,
                                      c16, h, h16, hsum16, s, sz, s_up, sz_up, 0);
  }
}